// Round 6
// baseline (406.713 us; speedup 1.0000x reference)
//
#include <hip/hip_runtime.h>
#include <hip/hip_bf16.h>
#include <stdint.h>

typedef short v8s __attribute__((ext_vector_type(8)));
typedef float v16f __attribute__((ext_vector_type(16)));
typedef unsigned int u32;

constexpr int S = 2048, D = 128, KVBLK = 64, NT = S / KVBLK, BH = 64;
constexpr int QW = 32, WAVES = 8, QBLK = QW * WAVES;   // 256 q-rows/block

#define LOG2E_F 1.44269504f

__device__ __forceinline__ unsigned short f2bf(float x) {
    union { float f; uint32_t u; } v; v.f = x;
    uint32_t r = v.u + 0x7FFFu + ((v.u >> 16) & 1u);   // RNE
    return (unsigned short)(r >> 16);
}
__device__ __forceinline__ u32 cvtpk(float lo, float hi) {
    u32 r; asm("v_cvt_pk_bf16_f32 %0, %1, %2" : "=v"(r) : "v"(lo), "v"(hi)); return r;
}
__device__ __forceinline__ void gload_lds16(const void* g, void* l) {
    __builtin_amdgcn_global_load_lds(
        (const __attribute__((address_space(1))) unsigned int*)g,
        (__attribute__((address_space(3))) unsigned int*)l, 16, 0, 0);
}

// ---- fused prepass: K f32->bf16 [bh][kv][d]; V f32 -> bf16 transposed [bh][d][kv]
__global__ __launch_bounds__(256)
void prep_kernel(const float* __restrict__ Kg, const float* __restrict__ Vg,
                 short* __restrict__ Kb, short* __restrict__ VtG)
{
    __shared__ __align__(16) short T[D * KVBLK];
    const int bh = blockIdx.y, kv0 = blockIdx.x * KVBLK;
    const int tid = threadIdx.x;
    {   // K convert (streaming)
        const float* kp = Kg + ((size_t)bh * S + kv0) * D;
        short* kb = Kb + ((size_t)bh * S + kv0) * D;
        #pragma unroll
        for (int i = 0; i < 4; ++i) {
            int e = (i * 256 + tid) * 8;
            float4 a = *(const float4*)(kp + e), b = *(const float4*)(kp + e + 4);
            v8s t;
            t[0] = f2bf(a.x); t[1] = f2bf(a.y); t[2] = f2bf(a.z); t[3] = f2bf(a.w);
            t[4] = f2bf(b.x); t[5] = f2bf(b.y); t[6] = f2bf(b.z); t[7] = f2bf(b.w);
            *(v8s*)(kb + e) = t;
        }
    }
    {   // V transpose via LDS (elem swizzle kv ^= (d&7)<<3 keeps b128 reads clean)
        const float* vp = Vg + ((size_t)bh * S + kv0) * D;
        const int kv = tid >> 2, dg = tid & 3;
        #pragma unroll
        for (int s4 = 0; s4 < 4; ++s4) {
            float4 a = *(const float4*)(vp + (size_t)kv * D + s4 * 32 + dg * 8);
            float4 b = *(const float4*)(vp + (size_t)kv * D + s4 * 32 + dg * 8 + 4);
            float vv[8] = {a.x, a.y, a.z, a.w, b.x, b.y, b.z, b.w};
            #pragma unroll
            for (int j = 0; j < 8; ++j) {
                int d = s4 * 32 + dg * 8 + j;
                T[d * KVBLK + (kv ^ ((d & 7) << 3))] = (short)f2bf(vv[j]);
            }
        }
        __syncthreads();
        const int s = tid & 7;
        #pragma unroll
        for (int p = 0; p < 4; ++p) {
            int d = p * 32 + (tid >> 3);
            v8s w = *(const v8s*)(&T[d * KVBLK + ((s ^ (d & 7)) << 3)]);
            *(v8s*)(VtG + (size_t)bh * D * S + (size_t)d * S + kv0 + s * 8) = w;
        }
    }
}

// ---- main fused attention: 8 waves x 32 q-rows, 32x32x16 MFMA ---------------
// LDS 48KB (K dbuf 2x16KB + V single 16KB) -> 2 blocks/CU resident (4 waves/SIMD)
__global__ __launch_bounds__(512, 2)
void fattn_kernel(const float* __restrict__ Qg, const short* __restrict__ Kb,
                  const short* __restrict__ Vb, float* __restrict__ Og)
{
    __shared__ __align__(16) short Ks[2][KVBLK * D];   // [kv][d], slot16B ^= kv&7
    __shared__ __align__(16) short Vt[D * KVBLK];      // [d][kv], slot16B ^= d&7

    const int tid = threadIdx.x, wave = tid >> 6, lane = tid & 63;
    const int l31 = lane & 31, h = lane >> 5;

    // XCD swizzle: head bh lands on XCD bh&7; 8 q-blocks of a head share the XCD
    const int bid = blockIdx.x;
    const int bh = (bid & 7) | ((bid >> 6) << 3);
    const int qt = (bid >> 3) & 7;
    const int q0 = qt * QBLK + wave * QW;
    const size_t base = (size_t)bh * S * D;

    const float SCALE = LOG2E_F * LOG2E_F * 0.08838834764831845f; // log2e^2/sqrt(128)

    // Q B-operand frags: lane holds Q[q0+l31][kst*16 + h*8 + j]
    v8s qf[8];
    {
        const float* qp = Qg + base + (size_t)(q0 + l31) * D + h * 8;
        #pragma unroll
        for (int kst = 0; kst < 8; ++kst) {
            float4 a = *(const float4*)(qp + kst * 16);
            float4 b = *(const float4*)(qp + kst * 16 + 4);
            union { u32 w[4]; v8s v; } qu;
            qu.w[0] = cvtpk(a.x * SCALE, a.y * SCALE);
            qu.w[1] = cvtpk(a.z * SCALE, a.w * SCALE);
            qu.w[2] = cvtpk(b.x * SCALE, b.y * SCALE);
            qu.w[3] = cvtpk(b.z * SCALE, b.w * SCALE);
            qf[kst] = qu.v;
        }
    }

    v16f o[4];
    #pragma unroll
    for (int i = 0; i < 4; ++i)
        #pragma unroll
        for (int r = 0; r < 16; ++r) o[i][r] = 0.f;
    float m_run = -1e30f, l_run = 0.f;

    auto stageK = [&](int buf, int kv0) {
        #pragma unroll
        for (int i = 0; i < 2; ++i) {           // chunk = 4 rows x 256B
            int ch = wave * 2 + i;
            int row = ch * 4 + (lane >> 4);
            int sl = lane & 15;
            const short* src = Kb + base + (size_t)(kv0 + row) * D + ((sl ^ (row & 7)) << 3);
            gload_lds16(src, &Ks[buf][ch * 512]);
        }
    };
    auto stageV = [&](int kv0) {
        #pragma unroll
        for (int i = 0; i < 2; ++i) {           // chunk = 8 d-rows x 128B
            int ch = wave * 2 + i;
            int d = ch * 8 + (lane >> 3);
            int sl = lane & 7;
            const short* src = Vb + base + (size_t)d * S + kv0 + ((sl ^ (d & 7)) << 3);
            gload_lds16(src, &Vt[ch * 512]);
        }
    };

    stageK(0, 0);
    __syncthreads();   // K(0) ready

    for (int it = 0; it < NT; ++it) {
        const int c = it & 1;
        stageV(it * KVBLK);                                // V(t) in flight
        if (it + 1 < NT) stageK(c ^ 1, (it + 1) * KVBLK);  // K(t+1) in flight

        const short* ks = &Ks[c][0];

        // ---- QK^T swapped: S^T[kv][q], C: col=l31=q, row=kv_local
        v16f s0, s1;
        #pragma unroll
        for (int r = 0; r < 16; ++r) { s0[r] = 0.f; s1[r] = 0.f; }
        __builtin_amdgcn_s_setprio(1);
        #pragma unroll
        for (int kst = 0; kst < 8; ++kst) {
            int sl = (kst * 2 + h) ^ (l31 & 7);
            v8s k0 = *(const v8s*)(&ks[l31 * D + sl * 8]);
            s0 = __builtin_amdgcn_mfma_f32_32x32x16_bf16(k0, qf[kst], s0, 0, 0, 0);
            v8s k1 = *(const v8s*)(&ks[(32 + l31) * D + sl * 8]);
            s1 = __builtin_amdgcn_mfma_f32_32x32x16_bf16(k1, qf[kst], s1, 0, 0, 0);
        }
        __builtin_amdgcn_s_setprio(0);

        // ---- online softmax: q = l31 is lane-local; rows split lane vs lane^32
        float tm = s0[0];
        #pragma unroll
        for (int r = 1; r < 16; ++r) tm = fmaxf(tm, s0[r]);
        #pragma unroll
        for (int r = 0; r < 16; ++r) tm = fmaxf(tm, s1[r]);
        tm = fmaxf(tm, __shfl_xor(tm, 32));

        bool skip = __all(tm <= m_run + 8.f);     // T13 defer-max, THR=8
        if (!skip) {
            float m_new = fmaxf(m_run, tm);
            float alpha = exp2f(m_run - m_new);
            #pragma unroll
            for (int i = 0; i < 4; ++i)
                #pragma unroll
                for (int r = 0; r < 16; ++r) o[i][r] *= alpha;
            l_run *= alpha;
            m_run = m_new;
        }
        float ts = 0.f;
        #pragma unroll
        for (int r = 0; r < 16; ++r) { s0[r] = exp2f(s0[r] - m_run); ts += s0[r]; }
        #pragma unroll
        for (int r = 0; r < 16; ++r) { s1[r] = exp2f(s1[r] - m_run); ts += s1[r]; }
        ts += __shfl_xor(ts, 32);
        l_run += ts;

        // ---- T12: P -> bf16 B-operand in-register (cvt_pk + permlane32_swap)
        v8s pf[4];
        #pragma unroll
        for (int ks2 = 0; ks2 < 4; ++ks2) {
            const v16f& P = (ks2 < 2) ? s0 : s1;
            int rb = (ks2 & 1) * 8;
            u32 a  = cvtpk(P[rb + 0], P[rb + 1]);
            u32 b  = cvtpk(P[rb + 2], P[rb + 3]);
            u32 cc = cvtpk(P[rb + 4], P[rb + 5]);
            u32 dd = cvtpk(P[rb + 6], P[rb + 7]);
            asm volatile("v_permlane32_swap_b32 %0, %1" : "+v"(a), "+v"(cc));
            asm volatile("v_permlane32_swap_b32 %0, %1" : "+v"(b), "+v"(dd));
            union { u32 w[4]; v8s v; } pu;
            pu.w[0] = a; pu.w[1] = b; pu.w[2] = cc; pu.w[3] = dd;
            pf[ks2] = pu.v;
        }

        __syncthreads();   // Bmid: drains vmcnt -> V(t) (and K(t+1)) fully in LDS

        // ---- PV: O^T += V^T · P^T
        __builtin_amdgcn_s_setprio(1);
        #pragma unroll
        for (int dt = 0; dt < 4; ++dt) {
            int d = dt * 32 + l31;
            #pragma unroll
            for (int ks2 = 0; ks2 < 4; ++ks2) {
                int sl = (ks2 * 2 + h) ^ (d & 7);
                v8s vf = *(const v8s*)(&Vt[d * KVBLK + sl * 8]);
                o[dt] = __builtin_amdgcn_mfma_f32_32x32x16_bf16(vf, pf[ks2], o[dt], 0, 0, 0);
            }
        }
        __builtin_amdgcn_s_setprio(0);

        __syncthreads();   // Bend: all PV reads of Vt done before next iter's writes
    }

    // ---- epilogue: O[q][d] = o / l_run; regs g*4..g*4+3 are 4 consecutive d
    float inv = 1.f / l_run;
    float* op = Og + base + (size_t)(q0 + l31) * D;
    #pragma unroll
    for (int dt = 0; dt < 4; ++dt)
        #pragma unroll
        for (int g = 0; g < 4; ++g) {
            float4 w;
            w.x = o[dt][g * 4 + 0] * inv; w.y = o[dt][g * 4 + 1] * inv;
            w.z = o[dt][g * 4 + 2] * inv; w.w = o[dt][g * 4 + 3] * inv;
            *(float4*)(op + dt * 32 + g * 8 + 4 * h) = w;
        }
}

extern "C" void kernel_launch(void* const* d_in, const int* in_sizes, int n_in,
                              void* d_out, int out_size, void* d_ws, size_t ws_size,
                              hipStream_t stream) {
    const float* Q = (const float*)d_in[0];
    const float* K = (const float*)d_in[1];
    const float* V = (const float*)d_in[2];
    float* O = (float*)d_out;

    short* Kb  = (short*)d_ws;                 // 33.55 MB
    short* VtG = Kb + (size_t)BH * S * D;      // 33.55 MB

    prep_kernel<<<dim3(NT, BH), dim3(256), 0, stream>>>(K, V, Kb, VtG);
    fattn_kernel<<<dim3(BH * 8), dim3(512), 0, stream>>>(Q, Kb, VtG, O);
}

// Round 7
// 375.220 us; speedup vs baseline: 1.0839x; 1.0839x over previous
//
#include <hip/hip_runtime.h>
#include <hip/hip_bf16.h>
#include <stdint.h>

typedef short v8s __attribute__((ext_vector_type(8)));
typedef float v16f __attribute__((ext_vector_type(16)));
typedef unsigned int u32;

constexpr int S = 2048, D = 128, KVBLK = 64, NT = S / KVBLK, BH = 64;
constexpr int QW = 32, WAVES = 8, QBLK = QW * WAVES;   // 256 q-rows/block

#define LOG2E_F 1.44269504f

__device__ __forceinline__ unsigned short f2bf(float x) {
    union { float f; uint32_t u; } v; v.f = x;
    uint32_t r = v.u + 0x7FFFu + ((v.u >> 16) & 1u);   // RNE
    return (unsigned short)(r >> 16);
}
__device__ __forceinline__ u32 cvtpk(float lo, float hi) {
    u32 r; asm("v_cvt_pk_bf16_f32 %0, %1, %2" : "=v"(r) : "v"(lo), "v"(hi)); return r;
}
__device__ __forceinline__ void gload_lds16(const void* g, void* l) {
    __builtin_amdgcn_global_load_lds(
        (const __attribute__((address_space(1))) unsigned int*)g,
        (__attribute__((address_space(3))) unsigned int*)l, 16, 0, 0);
}

// ---- fused prepass: K f32->bf16 [bh][kv][d]; V f32 -> bf16 transposed [bh][d][kv]
__global__ __launch_bounds__(256)
void prep_kernel(const float* __restrict__ Kg, const float* __restrict__ Vg,
                 short* __restrict__ Kb, short* __restrict__ VtG)
{
    __shared__ __align__(16) short T[D * KVBLK];
    const int bh = blockIdx.y, kv0 = blockIdx.x * KVBLK;
    const int tid = threadIdx.x;
    {   // K convert (streaming)
        const float* kp = Kg + ((size_t)bh * S + kv0) * D;
        short* kb = Kb + ((size_t)bh * S + kv0) * D;
        #pragma unroll
        for (int i = 0; i < 4; ++i) {
            int e = (i * 256 + tid) * 8;
            float4 a = *(const float4*)(kp + e), b = *(const float4*)(kp + e + 4);
            v8s t;
            t[0] = f2bf(a.x); t[1] = f2bf(a.y); t[2] = f2bf(a.z); t[3] = f2bf(a.w);
            t[4] = f2bf(b.x); t[5] = f2bf(b.y); t[6] = f2bf(b.z); t[7] = f2bf(b.w);
            *(v8s*)(kb + e) = t;
        }
    }
    {   // V transpose via LDS (elem swizzle kv ^= (d&7)<<3 keeps b128 reads clean)
        const float* vp = Vg + ((size_t)bh * S + kv0) * D;
        const int kv = tid >> 2, dg = tid & 3;
        #pragma unroll
        for (int s4 = 0; s4 < 4; ++s4) {
            float4 a = *(const float4*)(vp + (size_t)kv * D + s4 * 32 + dg * 8);
            float4 b = *(const float4*)(vp + (size_t)kv * D + s4 * 32 + dg * 8 + 4);
            float vv[8] = {a.x, a.y, a.z, a.w, b.x, b.y, b.z, b.w};
            #pragma unroll
            for (int j = 0; j < 8; ++j) {
                int d = s4 * 32 + dg * 8 + j;
                T[d * KVBLK + (kv ^ ((d & 7) << 3))] = (short)f2bf(vv[j]);
            }
        }
        __syncthreads();
        const int s = tid & 7;
        #pragma unroll
        for (int p = 0; p < 4; ++p) {
            int d = p * 32 + (tid >> 3);
            v8s w = *(const v8s*)(&T[d * KVBLK + ((s ^ (d & 7)) << 3)]);
            *(v8s*)(VtG + (size_t)bh * D * S + (size_t)d * S + kv0 + s * 8) = w;
        }
    }
}

// ---- main fused attention: 8 waves x 32 q-rows, 32x32x16 MFMA ---------------
// T15 pipeline: per iter QK^T(t) || softmax(t-1) || PV(t-1); 1 barrier/iter.
// LDS 64KB: K dbuf 2x16KB + V dbuf 2x16KB.
__global__ __launch_bounds__(512, 2)
void fattn_kernel(const float* __restrict__ Qg, const short* __restrict__ Kb,
                  const short* __restrict__ Vb, float* __restrict__ Og)
{
    __shared__ __align__(16) short Ks[2][KVBLK * D];   // [kv][d], slot16B ^= kv&7
    __shared__ __align__(16) short Vt[2][D * KVBLK];   // [d][kv], slot16B ^= d&7

    const int tid = threadIdx.x, wave = tid >> 6, lane = tid & 63;
    const int l31 = lane & 31, h = lane >> 5;

    // XCD swizzle: head bh lands on XCD bh&7; 8 q-blocks of a head share the XCD
    const int bid = blockIdx.x;
    const int bh = (bid & 7) | ((bid >> 6) << 3);
    const int qt = (bid >> 3) & 7;
    const int q0 = qt * QBLK + wave * QW;
    const size_t base = (size_t)bh * S * D;

    const float SCALE = LOG2E_F * LOG2E_F * 0.08838834764831845f; // log2e^2/sqrt(128)

    // Q B-operand frags: lane holds Q[q0+l31][kst*16 + h*8 + j]
    v8s qf[8];
    {
        const float* qp = Qg + base + (size_t)(q0 + l31) * D + h * 8;
        #pragma unroll
        for (int kst = 0; kst < 8; ++kst) {
            float4 a = *(const float4*)(qp + kst * 16);
            float4 b = *(const float4*)(qp + kst * 16 + 4);
            union { u32 w[4]; v8s v; } qu;
            qu.w[0] = cvtpk(a.x * SCALE, a.y * SCALE);
            qu.w[1] = cvtpk(a.z * SCALE, a.w * SCALE);
            qu.w[2] = cvtpk(b.x * SCALE, b.y * SCALE);
            qu.w[3] = cvtpk(b.z * SCALE, b.w * SCALE);
            qf[kst] = qu.v;
        }
    }

    v16f o[4];
    #pragma unroll
    for (int i = 0; i < 4; ++i)
        #pragma unroll
        for (int r = 0; r < 16; ++r) o[i][r] = 0.f;
    float m_run = -1e30f, l_run = 0.f;

    auto stageK = [&](int buf, int kv0) {
        #pragma unroll
        for (int i = 0; i < 2; ++i) {           // chunk = 4 rows x 256B
            int ch = wave * 2 + i;
            int row = ch * 4 + (lane >> 4);
            int sl = lane & 15;
            const short* src = Kb + base + (size_t)(kv0 + row) * D + ((sl ^ (row & 7)) << 3);
            gload_lds16(src, &Ks[buf][ch * 512]);
        }
    };
    auto stageV = [&](int buf, int kv0) {
        #pragma unroll
        for (int i = 0; i < 2; ++i) {           // chunk = 8 d-rows x 128B
            int ch = wave * 2 + i;
            int d = ch * 8 + (lane >> 3);
            int sl = lane & 7;
            const short* src = Vb + base + (size_t)d * S + kv0 + ((sl ^ (d & 7)) << 3);
            gload_lds16(src, &Vt[buf][ch * 512]);
        }
    };

    // QK^T (swapped): S^T[kv][q]; C: col=l31=q, row=kv_local
    auto QKT = [&](const short* ks, v16f& t0, v16f& t1) {
        #pragma unroll
        for (int r = 0; r < 16; ++r) { t0[r] = 0.f; t1[r] = 0.f; }
        __builtin_amdgcn_s_setprio(1);
        #pragma unroll
        for (int kst = 0; kst < 8; ++kst) {
            int sl = (kst * 2 + h) ^ (l31 & 7);
            v8s k0 = *(const v8s*)(&ks[l31 * D + sl * 8]);
            t0 = __builtin_amdgcn_mfma_f32_32x32x16_bf16(k0, qf[kst], t0, 0, 0, 0);
            v8s k1 = *(const v8s*)(&ks[(32 + l31) * D + sl * 8]);
            t1 = __builtin_amdgcn_mfma_f32_32x32x16_bf16(k1, qf[kst], t1, 0, 0, 0);
        }
        __builtin_amdgcn_s_setprio(0);
    };

    // online softmax of a finished S-tile + pack into pf (T12 + T13)
    auto SMAX = [&](v16f& t0, v16f& t1, v8s* pf) {
        float tm = t0[0];
        #pragma unroll
        for (int r = 1; r < 16; ++r) tm = fmaxf(tm, t0[r]);
        #pragma unroll
        for (int r = 0; r < 16; ++r) tm = fmaxf(tm, t1[r]);
        tm = fmaxf(tm, __shfl_xor(tm, 32));
        bool skip = __all(tm <= m_run + 8.f);     // defer-max, THR=8
        if (!skip) {
            float m_new = fmaxf(m_run, tm);
            float alpha = exp2f(m_run - m_new);
            #pragma unroll
            for (int i = 0; i < 4; ++i)
                #pragma unroll
                for (int r = 0; r < 16; ++r) o[i][r] *= alpha;
            l_run *= alpha;
            m_run = m_new;
        }
        float ts = 0.f;
        #pragma unroll
        for (int r = 0; r < 16; ++r) { t0[r] = exp2f(t0[r] - m_run); ts += t0[r]; }
        #pragma unroll
        for (int r = 0; r < 16; ++r) { t1[r] = exp2f(t1[r] - m_run); ts += t1[r]; }
        ts += __shfl_xor(ts, 32);
        l_run += ts;
        #pragma unroll
        for (int ks2 = 0; ks2 < 4; ++ks2) {
            const v16f& P = (ks2 < 2) ? t0 : t1;
            int rb = (ks2 & 1) * 8;
            u32 a  = cvtpk(P[rb + 0], P[rb + 1]);
            u32 b  = cvtpk(P[rb + 2], P[rb + 3]);
            u32 cc = cvtpk(P[rb + 4], P[rb + 5]);
            u32 dd = cvtpk(P[rb + 6], P[rb + 7]);
            asm volatile("v_permlane32_swap_b32 %0, %1" : "+v"(a), "+v"(cc));
            asm volatile("v_permlane32_swap_b32 %0, %1" : "+v"(b), "+v"(dd));
            union { u32 w[4]; v8s v; } pu;
            pu.w[0] = a; pu.w[1] = b; pu.w[2] = cc; pu.w[3] = dd;
            pf[ks2] = pu.v;
        }
    };

    auto PV = [&](const short* vt, const v8s* pf) {
        __builtin_amdgcn_s_setprio(1);
        #pragma unroll
        for (int dt = 0; dt < 4; ++dt) {
            int d = dt * 32 + l31;
            #pragma unroll
            for (int ks2 = 0; ks2 < 4; ++ks2) {
                int sl = (ks2 * 2 + h) ^ (d & 7);
                v8s vf = *(const v8s*)(&vt[d * KVBLK + sl * 8]);
                o[dt] = __builtin_amdgcn_mfma_f32_32x32x16_bf16(vf, pf[ks2], o[dt], 0, 0, 0);
            }
        }
        __builtin_amdgcn_s_setprio(0);
    };

    v16f sA0, sA1, sB0, sB1;
    v8s pfA[4], pfB[4];

    // ---- prologue
    stageK(0, 0);
    __syncthreads();                 // K(0) ready
    stageV(0, 0);
    stageK(1, KVBLK);
    QKT(&Ks[0][0], sA0, sA1);        // tile 0 scores
    __syncthreads();                 // V(0), K(1) ready

    // ---- main loop: pairs (t, t+1), t = 1,3,...,29  (covers tiles 1..30)
    #pragma unroll 1
    for (int tt = 1; tt <= NT - 3; tt += 2) {
        // step t=tt (odd): prev state A, cur B
        stageV(tt & 1, tt * KVBLK);
        stageK((tt + 1) & 1, (tt + 1) * KVBLK);
        QKT(&Ks[tt & 1][0], sB0, sB1);
        SMAX(sA0, sA1, pfA);
        PV(&Vt[(tt - 1) & 1][0], pfA);
        __syncthreads();
        // step t=tt+1 (even): prev state B, cur A
        const int te = tt + 1;
        stageV(te & 1, te * KVBLK);
        stageK((te + 1) & 1, (te + 1) * KVBLK);
        QKT(&Ks[te & 1][0], sA0, sA1);
        SMAX(sB0, sB1, pfB);
        PV(&Vt[(te - 1) & 1][0], pfB);
        __syncthreads();
    }

    // ---- tail: t = NT-1 = 31 (odd): prev A, cur B; no further K to stage
    stageV((NT - 1) & 1, (NT - 1) * KVBLK);
    QKT(&Ks[(NT - 1) & 1][0], sB0, sB1);
    SMAX(sA0, sA1, pfA);
    PV(&Vt[(NT - 2) & 1][0], pfA);
    __syncthreads();                 // V(31) ready
    SMAX(sB0, sB1, pfB);
    PV(&Vt[(NT - 1) & 1][0], pfB);

    // ---- epilogue: O[q][d] = o / l_run; regs g*4..g*4+3 are 4 consecutive d
    float inv = 1.f / l_run;
    float* op = Og + base + (size_t)(q0 + l31) * D;
    #pragma unroll
    for (int dt = 0; dt < 4; ++dt)
        #pragma unroll
        for (int g = 0; g < 4; ++g) {
            float4 w;
            w.x = o[dt][g * 4 + 0] * inv; w.y = o[dt][g * 4 + 1] * inv;
            w.z = o[dt][g * 4 + 2] * inv; w.w = o[dt][g * 4 + 3] * inv;
            *(float4*)(op + dt * 32 + g * 8 + 4 * h) = w;
        }
}

extern "C" void kernel_launch(void* const* d_in, const int* in_sizes, int n_in,
                              void* d_out, int out_size, void* d_ws, size_t ws_size,
                              hipStream_t stream) {
    const float* Q = (const float*)d_in[0];
    const float* K = (const float*)d_in[1];
    const float* V = (const float*)d_in[2];
    float* O = (float*)d_out;

    short* Kb  = (short*)d_ws;                 // 33.55 MB
    short* VtG = Kb + (size_t)BH * S * D;      // 33.55 MB

    prep_kernel<<<dim3(NT, BH), dim3(256), 0, stream>>>(K, V, Kb, VtG);
    fattn_kernel<<<dim3(BH * 8), dim3(512), 0, stream>>>(Q, Kb, VtG, O);
}